// Round 14
// baseline (289.961 us; speedup 1.0000x reference)
//
#include <hip/hip_runtime.h>

typedef unsigned short u16;
typedef short s16x8 __attribute__((ext_vector_type(8)));
typedef float f32x4 __attribute__((ext_vector_type(4)));

__device__ __forceinline__ float bf2f(u16 u) {
  return __uint_as_float(((unsigned)u) << 16);
}
__device__ __forceinline__ u16 f2bf(float f) {
  unsigned x = __float_as_uint(f);
  return (u16)((x + 0x7fffu + ((x >> 16) & 1u)) >> 16);
}

typedef unsigned __attribute__((address_space(1))) g_u32;
typedef unsigned __attribute__((address_space(3))) l_u32;
// async global->LDS DMA, 16B/lane: LDS dest = uniform base + lane*16
__device__ __forceinline__ void gload16(const u16* g, char* l) {
  __builtin_amdgcn_global_load_lds((const g_u32*)(const void*)g,
                                   (l_u32*)(void*)l, 16, 0, 0);
}

// ---------------------------------------------------------------------------
// Wqkv fp32 [576][192] -> bf16. grid 54, block 256
// ---------------------------------------------------------------------------
__global__ __launch_bounds__(256) void wcvt_k(
    const float* __restrict__ W, u16* __restrict__ Wb)
{
  const int i = (blockIdx.x * 256 + threadIdx.x) * 8;
  const float4 f0 = *(const float4*)(W + i);
  const float4 f1 = *(const float4*)(W + i + 4);
  union { s16x8 v; u16 u[8]; } pk;
  pk.u[0]=f2bf(f0.x); pk.u[1]=f2bf(f0.y); pk.u[2]=f2bf(f0.z); pk.u[3]=f2bf(f0.w);
  pk.u[4]=f2bf(f1.x); pk.u[5]=f2bf(f1.y); pk.u[6]=f2bf(f1.z); pk.u[7]=f2bf(f1.w);
  *(s16x8*)(Wb + i) = pk.v;
}

// ---------------------------------------------------------------------------
// Transpose [C=192][16384] (fp32 or bf16 input) -> [16384][192] bf16
// grid (3 c-tiles, 512 p-tiles, 8 b), block 256   [r3-verified]
// ---------------------------------------------------------------------------
template<bool IN_FP32>
__global__ __launch_bounds__(256) void transpose_k(
    const void* __restrict__ inp, u16* __restrict__ outp,
    long batchStride, int chanOffset)
{
  __shared__ float lds[64][33];
  const int c0 = blockIdx.x * 64, p0 = blockIdx.y * 32, b = blockIdx.z;
  const int t = threadIdx.x;
  {
    const int r = t >> 3, pq = (t & 7) * 4;
    #pragma unroll
    for (int i = 0; i < 2; i++) {
      const int c = r + i * 32;
      const long base = (long)b * batchStride + (long)(chanOffset + c0 + c) * 16384 + p0 + pq;
      if (IN_FP32) {
        const float4 v = *(const float4*)((const float*)inp + base);
        lds[c][pq+0] = v.x; lds[c][pq+1] = v.y; lds[c][pq+2] = v.z; lds[c][pq+3] = v.w;
      } else {
        const u16* s = (const u16*)inp + base;
        lds[c][pq+0] = bf2f(s[0]); lds[c][pq+1] = bf2f(s[1]);
        lds[c][pq+2] = bf2f(s[2]); lds[c][pq+3] = bf2f(s[3]);
      }
    }
  }
  __syncthreads();
  const int p = t >> 3, c8 = (t & 7) * 8;
  union { s16x8 v; u16 u[8]; } pk;
  #pragma unroll
  for (int j = 0; j < 8; j++) pk.u[j] = f2bf(lds[c8 + j][p]);
  *(s16x8*)(outp + ((long)b * 16384 + p0 + p) * 192 + c0 + c8) = pk.v;
}

// ---------------------------------------------------------------------------
// DMA-staged NT GEMM (r5 skeleton): out[b][m][p] = sum_k A[m][k]*B[n0+p][k].
// K=192, BM=64, BN=128, BK=64, 4 waves, 24KB LDS. Both operands staged by
// global_load_lds width-16 with pre-swizzled global source. [r13-verified]
// grid MT*1024, block 256
// ---------------------------------------------------------------------------
template<bool OUT_BF16, int MT>
__global__ __launch_bounds__(256, 4) void gemm_dma(
    const u16* __restrict__ Ab, const u16* __restrict__ Bb,
    void* __restrict__ outp, long aStride)
{
  __shared__ char smem[24576];
  char* const As = smem;          // [64 rows][8 swz 16B-blk]
  char* const Bs = smem + 8192;   // [128 rows][8 swz 16B-blk]
  const int t = threadIdx.x, wave = t >> 6, lane = t & 63;
  const int l15 = lane & 15, l4 = lane >> 4;
  const int i = blockIdx.x;
  const int xcd = i & 7, kk = i >> 3;
  const int n  = xcd + 8 * (kk / MT);
  const int m0 = (kk % MT) * 64;
  const long n0 = (long)n * 128;
  const int b  = (int)(n0 >> 14);
  const int p0 = (int)(n0 & 16383);
  const int irow = lane >> 3, iblk = lane & 7;

  f32x4 acc[4][2];
  #pragma unroll
  for (int mi = 0; mi < 4; mi++)
    #pragma unroll
    for (int ni = 0; ni < 2; ni++) acc[mi][ni] = (f32x4){0.f,0.f,0.f,0.f};

  const u16* const Abase = Ab + (long)b * aStride;

  for (int kc = 0; kc < 192; kc += 64) {
    if (kc) __syncthreads();
    #pragma unroll
    for (int a = 0; a < 2; a++) {
      const int row = (wave*2 + a)*8 + irow;
      const int sb  = iblk ^ (row & 7);
      gload16(Abase + (long)(m0 + row)*192 + kc + sb*8,
              As + (wave*2 + a)*1024);
    }
    #pragma unroll
    for (int a = 0; a < 4; a++) {
      const int row = (wave*4 + a)*8 + irow;
      const int sb  = iblk ^ (row & 7);
      gload16(Bb + (n0 + row)*192 + kc + sb*8,
              Bs + (wave*4 + a)*1024);
    }
    __syncthreads();
    #pragma unroll
    for (int kq = 0; kq < 2; kq++) {
      const int kb = kq*4 + l4;
      s16x8 af[4], bfr[2];
      #pragma unroll
      for (int mi = 0; mi < 4; mi++) {
        const int row = mi*16 + l15;
        af[mi] = *(const s16x8*)(As + row*128 + ((kb ^ (row&7)) << 4));
      }
      #pragma unroll
      for (int ni = 0; ni < 2; ni++) {
        const int row = wave*32 + ni*16 + l15;
        bfr[ni] = *(const s16x8*)(Bs + row*128 + ((kb ^ (row&7)) << 4));
      }
      #pragma unroll
      for (int mi = 0; mi < 4; mi++)
        #pragma unroll
        for (int ni = 0; ni < 2; ni++)
          acc[mi][ni] = __builtin_amdgcn_mfma_f32_16x16x32_bf16(
              af[mi], bfr[ni], acc[mi][ni], 0, 0, 0);
    }
  }

  const long outBase = (long)b * (MT*64) * 16384;
  #pragma unroll
  for (int mi = 0; mi < 4; mi++) {
    #pragma unroll
    for (int ni = 0; ni < 2; ni++) {
      const int col = p0 + wave*32 + ni*16 + l15;
      #pragma unroll
      for (int j = 0; j < 4; j++) {
        const int row = m0 + mi*16 + l4*4 + j;
        if (OUT_BF16) ((u16*)outp)[outBase + (long)row * 16384 + col] = f2bf(acc[mi][ni][j]);
        else          ((float*)outp)[outBase + (long)row * 16384 + col] = acc[mi][ni][j];
      }
    }
  }
}

// ---------------------------------------------------------------------------
// Depthwise 3x3 conv, padding 1, IN-PLACE on qkv (bf16).
// LDS [130][144] u16: row stride 288B (16B-aligned rows), pixel (gy,gx) at
// [(gy+1)*144 + 8 + gx], 8-col zero pads both sides -> ALL LDS accesses are
// aligned b128: staging 1 uint4 write, compute 9 ds_read_b128/iter (was 30
// scalar u16). Bank pattern <=2-way (free).
// grid (576, 8), block 256
// ---------------------------------------------------------------------------
__global__ __launch_bounds__(256) void dwconv_k(
    u16* __restrict__ qkv, const float* __restrict__ Wdw)
{
  __shared__ u16 lds[130*144];
  const int ch = blockIdx.x, b = blockIdx.y;
  u16* const base = qkv + ((long)b * 576 + ch) * 16384;
  const int t = threadIdx.x;

  {  // zero all (pads included): 37440 B = 2340 uint4
    uint4* z = (uint4*)lds;
    #pragma unroll
    for (int i = 0; i < 10; i++) {
      const int idx = t + i*256;
      if (idx < 2340) z[idx] = (uint4){0,0,0,0};
    }
  }
  float w[9];
  #pragma unroll
  for (int i = 0; i < 9; i++) w[i] = Wdw[ch*9 + i];
  __syncthreads();

  #pragma unroll
  for (int i = 0; i < 8; i++) {
    const int p = t + i*256;            // 2048 chunks of 8 u16
    const int y = p >> 4, x = (p & 15) * 8;
    *(uint4*)(&lds[(y+1)*144 + 8 + x]) = *(const uint4*)(base + y*128 + x);
  }
  __syncthreads();

  #pragma unroll
  for (int i = 0; i < 8; i++) {
    const int p = t + i*256;
    const int y = p >> 4, x = (p & 15) * 8;
    float r[3][10];
    #pragma unroll
    for (int dy = 0; dy < 3; dy++) {
      const u16* row = &lds[(y+dy)*144 + 8 + x];
      union { uint4 v; u16 u[8]; } c0, c1, c2;
      c0.v = *(const uint4*)(row - 8);
      c1.v = *(const uint4*)(row);
      c2.v = *(const uint4*)(row + 8);
      r[dy][0] = bf2f(c0.u[7]);
      #pragma unroll
      for (int j = 0; j < 8; j++) r[dy][j+1] = bf2f(c1.u[j]);
      r[dy][9] = bf2f(c2.u[0]);
    }
    float acc[8];
    #pragma unroll
    for (int xx = 0; xx < 8; xx++)
      acc[xx] = w[0]*r[0][xx] + w[1]*r[0][xx+1] + w[2]*r[0][xx+2]
              + w[3]*r[1][xx] + w[4]*r[1][xx+1] + w[5]*r[1][xx+2]
              + w[6]*r[2][xx] + w[7]*r[2][xx+1] + w[8]*r[2][xx+2];
    union { uint4 v; u16 u[8]; } st;
    #pragma unroll
    for (int xx = 0; xx < 8; xx++) st.u[xx] = f2bf(acc[xx]);
    *(uint4*)(base + y*128 + x) = st.v;
  }
}

// ---------------------------------------------------------------------------
// Gram: per (b,h) 48x48 self-product of rows U=[q*f ; k*f] over k-chunk 2048.
// grid (8 kc, 64 bh), block 256 (4 waves)
// ---------------------------------------------------------------------------
__global__ __launch_bounds__(256) void gram_k(
    const u16* __restrict__ qkv, const float* __restrict__ feature,
    float* __restrict__ Gp)
{
  __shared__ u16 us[48*128];
  __shared__ float red[4*2304];
  const int kc = blockIdx.x, bh = blockIdx.y;
  const int b = bh >> 3, h = bh & 7;
  const int t = threadIdx.x, wave = t >> 6, lane = t & 63;
  const int l15 = lane & 15, l4 = lane >> 4;
  const u16* const qbase = qkv + ((long)b*576 + h*24) * 16384;
  const u16* const kbase = qkv + ((long)b*576 + 192 + h*24) * 16384;
  const float* const fbase = feature + ((long)b*192 + h*24) * 16384;
  char* const usb = (char*)us;

  f32x4 acc[3][3];
  #pragma unroll
  for (int i = 0; i < 3; i++)
    #pragma unroll
    for (int j = 0; j < 3; j++) acc[i][j] = (f32x4){0.f, 0.f, 0.f, 0.f};

  for (int step = 0; step < 16; step++) {
    const int k0 = kc*2048 + step*128;
    #pragma unroll
    for (int i = 0; i < 3; i++) {
      const int idx = t + i*256;
      const int r = idx >> 5, d4 = idx & 31;
      const long po = (long)r*16384 + k0 + d4*4;
      const float4 f4 = *(const float4*)(fbase + po);
      union { uint2 v; u16 u[4]; } uq, uk, oq, ok;
      uq.v = *(const uint2*)(qbase + po);
      uk.v = *(const uint2*)(kbase + po);
      const float fv[4] = {f4.x, f4.y, f4.z, f4.w};
      #pragma unroll
      for (int j = 0; j < 4; j++) {
        oq.u[j] = f2bf(bf2f(uq.u[j]) * fv[j]);
        ok.u[j] = f2bf(bf2f(uk.u[j]) * fv[j]);
      }
      const int col = d4*4;
      const int sub = ((col&7)<<1);
      const int r2 = r + 24;
      *(uint2*)(usb + r *256 + (((col>>3) ^ (r &7)) << 4) + sub) = oq.v;
      *(uint2*)(usb + r2*256 + (((col>>3) ^ (r2&7)) << 4) + sub) = ok.v;
    }
    __syncthreads();
    {
      const int kb = wave*4 + l4;
      s16x8 fr[3];
      #pragma unroll
      for (int g = 0; g < 3; g++) {
        const int row = g*16 + l15;
        fr[g] = *(const s16x8*)(usb + row*256 + ((kb ^ (row&7)) << 4));
      }
      #pragma unroll
      for (int gm = 0; gm < 3; gm++)
        #pragma unroll
        for (int gn = 0; gn < 3; gn++)
          acc[gm][gn] = __builtin_amdgcn_mfma_f32_16x16x32_bf16(fr[gm], fr[gn], acc[gm][gn], 0, 0, 0);
    }
    __syncthreads();
  }
  #pragma unroll
  for (int gm = 0; gm < 3; gm++)
    #pragma unroll
    for (int gn = 0; gn < 3; gn++)
      #pragma unroll
      for (int j = 0; j < 4; j++) {
        const int r = gm*16 + l4*4 + j, s = gn*16 + l15;
        red[wave*2304 + r*48 + s] = acc[gm][gn][j];
      }
  __syncthreads();
  for (int idx = t; idx < 2304; idx += 256) {
    const float sum = red[idx] + red[2304+idx] + red[4608+idx] + red[6912+idx];
    Gp[((long)bh*8 + kc)*2304 + idx] = sum;
  }
}

// ---------------------------------------------------------------------------
// Finalize attention: reduce Gram over kc, normalize, temperature, softmax.
// grid 64 (bh), block 256
// ---------------------------------------------------------------------------
__global__ __launch_bounds__(256) void attnfin_k(
    const float* __restrict__ Gp, const float* __restrict__ temperature,
    float* __restrict__ attn)
{
  __shared__ float cross[576];
  __shared__ float qn[24], kn[24];
  const int bh = blockIdx.x, h = bh & 7;
  const int t = threadIdx.x;
  const float* const g = Gp + (long)bh * 8 * 2304;
  for (int idx = t; idx < 624; idx += 256) {
    float s = 0.f;
    if (idx < 576) {
      const int c = idx / 24, d = idx - c * 24;
      #pragma unroll
      for (int kc = 0; kc < 8; kc++) s += g[kc*2304 + c*48 + 24 + d];
      cross[idx] = s;
    } else {
      const int r = idx - 576;
      #pragma unroll
      for (int kc = 0; kc < 8; kc++) s += g[kc*2304 + r*48 + r];
      const float nv = fmaxf(sqrtf(s), 1e-12f);
      if (r < 24) qn[r] = nv; else kn[r-24] = nv;
    }
  }
  __syncthreads();
  if (t < 24) {
    const float tmp = temperature[h];
    const float qi = 1.f / qn[t];
    float vals[24];
    float m = -1e30f;
    #pragma unroll
    for (int d = 0; d < 24; d++) {
      const float v = cross[t*24 + d] * qi / kn[d] * tmp;
      vals[d] = v; m = fmaxf(m, v);
    }
    float s = 0.f;
    #pragma unroll
    for (int d = 0; d < 24; d++) { vals[d] = __expf(vals[d] - m); s += vals[d]; }
    const float inv = 1.f / s;
    #pragma unroll
    for (int d = 0; d < 24; d++) attn[(long)bh*576 + t*24 + d] = vals[d] * inv;
  }
}

// ---------------------------------------------------------------------------
// M2[b][o][g] = sum_c Wproj[o][h(g)*24+c] * attn[b][h(g)][c][d(g)]  (bf16)
// grid 1152, block 256
// ---------------------------------------------------------------------------
__global__ __launch_bounds__(256) void m2_k(
    const float* __restrict__ attn, const float* __restrict__ Wp,
    u16* __restrict__ M2)
{
  const int gid = blockIdx.x * 256 + threadIdx.x;
  const int g = gid % 192;
  const int rem = gid / 192;
  const int o = rem % 192;
  const int b = rem / 192;
  const int h = g / 24, d = g - h*24;
  const float* a = attn + ((long)(b*8 + h) * 24) * 24 + d;
  const float* w = Wp + (long)o * 192 + h * 24;
  float s = 0.f;
  #pragma unroll
  for (int c = 0; c < 24; c++) s += w[c] * a[c*24];
  M2[gid] = f2bf(s);
}

// ---------------------------------------------------------------------------
extern "C" void kernel_launch(void* const* d_in, const int* in_sizes, int n_in,
                              void* d_out, int out_size, void* d_ws, size_t ws_size,
                              hipStream_t stream) {
  const float* x    = (const float*)d_in[0];
  const float* fe   = (const float*)d_in[1];
  const float* Wqkv = (const float*)d_in[2];
  const float* Wdw  = (const float*)d_in[3];
  const float* Wpr  = (const float*)d_in[4];
  const float* temp = (const float*)d_in[5];

  char* ws = (char*)d_ws;
  u16*   xT  = (u16*)ws;                          // 50,331,648 B  [b*16384+p][192]
  u16*   vT  = xT;                                // reuse (xT dead after qkv GEMM)
  u16*   qkv = (u16*)(ws + 50331648L);            // 150,994,944 B [b][576][16384]
  float* Gp  = (float*)(ws + 201326592L);         // 4,718,592 B   [64][8][2304]
  float* attn= (float*)(ws + 206045184L);         // 147,456 B     [64][24][24]
  u16*   M2  = (u16*)(ws + 206192640L);           // 589,824 B     [b][192][192]
  u16*   Wb  = (u16*)(ws + 206782464L);           // 221,184 B     Wqkv bf16

  wcvt_k<<<54, 256, 0, stream>>>(Wqkv, Wb);
  transpose_k<true ><<<dim3(3,512,8), 256, 0, stream>>>(x, xT, 192L*16384, 0);
  gemm_dma<true, 9><<<9216, 256, 0, stream>>>(Wb, xT, qkv, 0);
  dwconv_k<<<dim3(576,8), 256, 0, stream>>>(qkv, Wdw);
  transpose_k<false><<<dim3(3,512,8), 256, 0, stream>>>(qkv, vT, 576L*16384, 384);
  gram_k<<<dim3(8,64), 256, 0, stream>>>(qkv, fe, Gp);
  attnfin_k<<<64, 256, 0, stream>>>(Gp, temp, attn);
  m2_k<<<1152, 256, 0, stream>>>(attn, Wpr, M2);
  gemm_dma<false, 3><<<3072, 256, 0, stream>>>(M2, vT, d_out, 36864L);
}

// Round 15
// 226.073 us; speedup vs baseline: 1.2826x; 1.2826x over previous
//
#include <hip/hip_runtime.h>

typedef unsigned short u16;
typedef short s16x8 __attribute__((ext_vector_type(8)));
typedef float f32x4 __attribute__((ext_vector_type(4)));

__device__ __forceinline__ float bf2f(u16 u) {
  return __uint_as_float(((unsigned)u) << 16);
}
__device__ __forceinline__ u16 f2bf(float f) {
  unsigned x = __float_as_uint(f);
  return (u16)((x + 0x7fffu + ((x >> 16) & 1u)) >> 16);
}

typedef unsigned __attribute__((address_space(1))) g_u32;
typedef unsigned __attribute__((address_space(3))) l_u32;
// async global->LDS DMA, 16B/lane: LDS dest = uniform base + lane*16
__device__ __forceinline__ void gload16(const u16* g, char* l) {
  __builtin_amdgcn_global_load_lds((const g_u32*)(const void*)g,
                                   (l_u32*)(void*)l, 16, 0, 0);
}

// ---------------------------------------------------------------------------
// Wqkv fp32 [576][192] -> bf16. grid 54, block 256
// ---------------------------------------------------------------------------
__global__ __launch_bounds__(256) void wcvt_k(
    const float* __restrict__ W, u16* __restrict__ Wb)
{
  const int i = (blockIdx.x * 256 + threadIdx.x) * 8;
  const float4 f0 = *(const float4*)(W + i);
  const float4 f1 = *(const float4*)(W + i + 4);
  union { s16x8 v; u16 u[8]; } pk;
  pk.u[0]=f2bf(f0.x); pk.u[1]=f2bf(f0.y); pk.u[2]=f2bf(f0.z); pk.u[3]=f2bf(f0.w);
  pk.u[4]=f2bf(f1.x); pk.u[5]=f2bf(f1.y); pk.u[6]=f2bf(f1.z); pk.u[7]=f2bf(f1.w);
  *(s16x8*)(Wb + i) = pk.v;
}

// ---------------------------------------------------------------------------
// Transpose [C=192][16384] (fp32 or bf16 input) -> [16384][192] bf16
// grid (3 c-tiles, 512 p-tiles, 8 b), block 256   [r3-verified]
// ---------------------------------------------------------------------------
template<bool IN_FP32>
__global__ __launch_bounds__(256) void transpose_k(
    const void* __restrict__ inp, u16* __restrict__ outp,
    long batchStride, int chanOffset)
{
  __shared__ float lds[64][33];
  const int c0 = blockIdx.x * 64, p0 = blockIdx.y * 32, b = blockIdx.z;
  const int t = threadIdx.x;
  {
    const int r = t >> 3, pq = (t & 7) * 4;
    #pragma unroll
    for (int i = 0; i < 2; i++) {
      const int c = r + i * 32;
      const long base = (long)b * batchStride + (long)(chanOffset + c0 + c) * 16384 + p0 + pq;
      if (IN_FP32) {
        const float4 v = *(const float4*)((const float*)inp + base);
        lds[c][pq+0] = v.x; lds[c][pq+1] = v.y; lds[c][pq+2] = v.z; lds[c][pq+3] = v.w;
      } else {
        const u16* s = (const u16*)inp + base;
        lds[c][pq+0] = bf2f(s[0]); lds[c][pq+1] = bf2f(s[1]);
        lds[c][pq+2] = bf2f(s[2]); lds[c][pq+3] = bf2f(s[3]);
      }
    }
  }
  __syncthreads();
  const int p = t >> 3, c8 = (t & 7) * 8;
  union { s16x8 v; u16 u[8]; } pk;
  #pragma unroll
  for (int j = 0; j < 8; j++) pk.u[j] = f2bf(lds[c8 + j][p]);
  *(s16x8*)(outp + ((long)b * 16384 + p0 + p) * 192 + c0 + c8) = pk.v;
}

// ---------------------------------------------------------------------------
// DMA-staged NT GEMM (r5 skeleton): out[b][m][p] = sum_k A[m][k]*B[n0+p][k].
// K=192, BM=64, BN=128, BK=64, 4 waves, 24KB LDS. Both operands staged by
// global_load_lds width-16 with pre-swizzled global source. [r13-verified]
// grid MT*1024, block 256
// ---------------------------------------------------------------------------
template<bool OUT_BF16, int MT>
__global__ __launch_bounds__(256, 4) void gemm_dma(
    const u16* __restrict__ Ab, const u16* __restrict__ Bb,
    void* __restrict__ outp, long aStride)
{
  __shared__ char smem[24576];
  char* const As = smem;          // [64 rows][8 swz 16B-blk]
  char* const Bs = smem + 8192;   // [128 rows][8 swz 16B-blk]
  const int t = threadIdx.x, wave = t >> 6, lane = t & 63;
  const int l15 = lane & 15, l4 = lane >> 4;
  const int i = blockIdx.x;
  const int xcd = i & 7, kk = i >> 3;
  const int n  = xcd + 8 * (kk / MT);
  const int m0 = (kk % MT) * 64;
  const long n0 = (long)n * 128;
  const int b  = (int)(n0 >> 14);
  const int p0 = (int)(n0 & 16383);
  const int irow = lane >> 3, iblk = lane & 7;

  f32x4 acc[4][2];
  #pragma unroll
  for (int mi = 0; mi < 4; mi++)
    #pragma unroll
    for (int ni = 0; ni < 2; ni++) acc[mi][ni] = (f32x4){0.f,0.f,0.f,0.f};

  const u16* const Abase = Ab + (long)b * aStride;

  for (int kc = 0; kc < 192; kc += 64) {
    if (kc) __syncthreads();
    #pragma unroll
    for (int a = 0; a < 2; a++) {
      const int row = (wave*2 + a)*8 + irow;
      const int sb  = iblk ^ (row & 7);
      gload16(Abase + (long)(m0 + row)*192 + kc + sb*8,
              As + (wave*2 + a)*1024);
    }
    #pragma unroll
    for (int a = 0; a < 4; a++) {
      const int row = (wave*4 + a)*8 + irow;
      const int sb  = iblk ^ (row & 7);
      gload16(Bb + (n0 + row)*192 + kc + sb*8,
              Bs + (wave*4 + a)*1024);
    }
    __syncthreads();
    #pragma unroll
    for (int kq = 0; kq < 2; kq++) {
      const int kb = kq*4 + l4;
      s16x8 af[4], bfr[2];
      #pragma unroll
      for (int mi = 0; mi < 4; mi++) {
        const int row = mi*16 + l15;
        af[mi] = *(const s16x8*)(As + row*128 + ((kb ^ (row&7)) << 4));
      }
      #pragma unroll
      for (int ni = 0; ni < 2; ni++) {
        const int row = wave*32 + ni*16 + l15;
        bfr[ni] = *(const s16x8*)(Bs + row*128 + ((kb ^ (row&7)) << 4));
      }
      #pragma unroll
      for (int mi = 0; mi < 4; mi++)
        #pragma unroll
        for (int ni = 0; ni < 2; ni++)
          acc[mi][ni] = __builtin_amdgcn_mfma_f32_16x16x32_bf16(
              af[mi], bfr[ni], acc[mi][ni], 0, 0, 0);
    }
  }

  const long outBase = (long)b * (MT*64) * 16384;
  #pragma unroll
  for (int mi = 0; mi < 4; mi++) {
    #pragma unroll
    for (int ni = 0; ni < 2; ni++) {
      const int col = p0 + wave*32 + ni*16 + l15;
      #pragma unroll
      for (int j = 0; j < 4; j++) {
        const int row = m0 + mi*16 + l4*4 + j;
        if (OUT_BF16) ((u16*)outp)[outBase + (long)row * 16384 + col] = f2bf(acc[mi][ni][j]);
        else          ((float*)outp)[outBase + (long)row * 16384 + col] = acc[mi][ni][j];
      }
    }
  }
}

// ---------------------------------------------------------------------------
// Depthwise 3x3 conv, padding 1, IN-PLACE on qkv (bf16).
// Sliding-window: thread owns 8px x 8rows; each LDS row read ONCE (10
// ds_read_b128 per thread for 64 outputs), prev/cur/next rows in registers,
// x-neighbors via shfl (edge-masked = zero padding). Staging: 1 aligned
// uint4 write per chunk into [130][144] (row-pads zeroed; col neighbors
// come from shfl so col-pads unused).
// grid (576, 8), block 256
// ---------------------------------------------------------------------------
__global__ __launch_bounds__(256) void dwconv_k(
    u16* __restrict__ qkv, const float* __restrict__ Wdw)
{
  __shared__ u16 lds[130*144];   // row stride 144 u16 = 288B; pixel (gy,gx) at [(gy+1)*144+8+gx]
  const int ch = blockIdx.x, b = blockIdx.y;
  u16* const base = qkv + ((long)b * 576 + ch) * 16384;
  const int t = threadIdx.x;

  // zero only pad rows 0 and 129 (36 uint4)
  if (t < 36) {
    uint4* z = (uint4*)lds;
    const int off = (t < 18) ? t : (129*18 + t - 18);
    z[off] = (uint4){0,0,0,0};
  }
  float w[9];
  #pragma unroll
  for (int i = 0; i < 9; i++) w[i] = Wdw[ch*9 + i];

  // stage plane: 1 aligned uint4 write per 8-px chunk
  #pragma unroll
  for (int i = 0; i < 8; i++) {
    const int p = t + i*256;            // 2048 chunks of 8 u16
    const int y = p >> 4, x = (p & 15) * 8;
    *(uint4*)(&lds[(y+1)*144 + 8 + x]) = *(const uint4*)(base + y*128 + x);
  }
  __syncthreads();

  const int xc = t & 15;        // x-chunk (8 px), x = xc*8
  const int yg = t >> 4;        // 0..15 -> rows yg*8 .. yg*8+7
  const int x  = xc * 8;
  const int y0 = yg * 8;

  // load one LDS row segment -> r[0..9] = [left px, own 8, right px]
  auto loadrow = [&](int gy, float* r) {
    union { uint4 v; u16 u[8]; } c;
    c.v = *(const uint4*)(&lds[(gy+1)*144 + 8 + x]);
    #pragma unroll
    for (int j = 0; j < 8; j++) r[j+1] = bf2f(c.u[j]);
    const float lf = __shfl_up(r[8], 1, 64);
    const float rf = __shfl_down(r[1], 1, 64);
    r[0] = (xc == 0)  ? 0.f : lf;
    r[9] = (xc == 15) ? 0.f : rf;
  };

  float r0[10], r1[10], r2[10];
  loadrow(y0 - 1, r0);
  loadrow(y0,     r1);
  #pragma unroll
  for (int yy = 0; yy < 8; yy++) {
    loadrow(y0 + yy + 1, r2);
    float acc[8];
    #pragma unroll
    for (int xx = 0; xx < 8; xx++)
      acc[xx] = w[0]*r0[xx] + w[1]*r0[xx+1] + w[2]*r0[xx+2]
              + w[3]*r1[xx] + w[4]*r1[xx+1] + w[5]*r1[xx+2]
              + w[6]*r2[xx] + w[7]*r2[xx+1] + w[8]*r2[xx+2];
    union { uint4 v; u16 u[8]; } st;
    #pragma unroll
    for (int xx = 0; xx < 8; xx++) st.u[xx] = f2bf(acc[xx]);
    *(uint4*)(base + (y0 + yy)*128 + x) = st.v;
    // rotate (full unroll -> SSA renames, no real copies)
    #pragma unroll
    for (int j = 0; j < 10; j++) { r0[j] = r1[j]; r1[j] = r2[j]; }
  }
}

// ---------------------------------------------------------------------------
// Gram: per (b,h) 48x48 self-product of rows U=[q*f ; k*f] over k-chunk 2048.
// grid (8 kc, 64 bh), block 256 (4 waves)
// ---------------------------------------------------------------------------
__global__ __launch_bounds__(256) void gram_k(
    const u16* __restrict__ qkv, const float* __restrict__ feature,
    float* __restrict__ Gp)
{
  __shared__ u16 us[48*128];
  __shared__ float red[4*2304];
  const int kc = blockIdx.x, bh = blockIdx.y;
  const int b = bh >> 3, h = bh & 7;
  const int t = threadIdx.x, wave = t >> 6, lane = t & 63;
  const int l15 = lane & 15, l4 = lane >> 4;
  const u16* const qbase = qkv + ((long)b*576 + h*24) * 16384;
  const u16* const kbase = qkv + ((long)b*576 + 192 + h*24) * 16384;
  const float* const fbase = feature + ((long)b*192 + h*24) * 16384;
  char* const usb = (char*)us;

  f32x4 acc[3][3];
  #pragma unroll
  for (int i = 0; i < 3; i++)
    #pragma unroll
    for (int j = 0; j < 3; j++) acc[i][j] = (f32x4){0.f, 0.f, 0.f, 0.f};

  for (int step = 0; step < 16; step++) {
    const int k0 = kc*2048 + step*128;
    #pragma unroll
    for (int i = 0; i < 3; i++) {
      const int idx = t + i*256;
      const int r = idx >> 5, d4 = idx & 31;
      const long po = (long)r*16384 + k0 + d4*4;
      const float4 f4 = *(const float4*)(fbase + po);
      union { uint2 v; u16 u[4]; } uq, uk, oq, ok;
      uq.v = *(const uint2*)(qbase + po);
      uk.v = *(const uint2*)(kbase + po);
      const float fv[4] = {f4.x, f4.y, f4.z, f4.w};
      #pragma unroll
      for (int j = 0; j < 4; j++) {
        oq.u[j] = f2bf(bf2f(uq.u[j]) * fv[j]);
        ok.u[j] = f2bf(bf2f(uk.u[j]) * fv[j]);
      }
      const int col = d4*4;
      const int sub = ((col&7)<<1);
      const int r2 = r + 24;
      *(uint2*)(usb + r *256 + (((col>>3) ^ (r &7)) << 4) + sub) = oq.v;
      *(uint2*)(usb + r2*256 + (((col>>3) ^ (r2&7)) << 4) + sub) = ok.v;
    }
    __syncthreads();
    {
      const int kb = wave*4 + l4;
      s16x8 fr[3];
      #pragma unroll
      for (int g = 0; g < 3; g++) {
        const int row = g*16 + l15;
        fr[g] = *(const s16x8*)(usb + row*256 + ((kb ^ (row&7)) << 4));
      }
      #pragma unroll
      for (int gm = 0; gm < 3; gm++)
        #pragma unroll
        for (int gn = 0; gn < 3; gn++)
          acc[gm][gn] = __builtin_amdgcn_mfma_f32_16x16x32_bf16(fr[gm], fr[gn], acc[gm][gn], 0, 0, 0);
    }
    __syncthreads();
  }
  #pragma unroll
  for (int gm = 0; gm < 3; gm++)
    #pragma unroll
    for (int gn = 0; gn < 3; gn++)
      #pragma unroll
      for (int j = 0; j < 4; j++) {
        const int r = gm*16 + l4*4 + j, s = gn*16 + l15;
        red[wave*2304 + r*48 + s] = acc[gm][gn][j];
      }
  __syncthreads();
  for (int idx = t; idx < 2304; idx += 256) {
    const float sum = red[idx] + red[2304+idx] + red[4608+idx] + red[6912+idx];
    Gp[((long)bh*8 + kc)*2304 + idx] = sum;
  }
}

// ---------------------------------------------------------------------------
// Finalize attention: reduce Gram over kc, normalize, temperature, softmax.
// grid 64 (bh), block 256
// ---------------------------------------------------------------------------
__global__ __launch_bounds__(256) void attnfin_k(
    const float* __restrict__ Gp, const float* __restrict__ temperature,
    float* __restrict__ attn)
{
  __shared__ float cross[576];
  __shared__ float qn[24], kn[24];
  const int bh = blockIdx.x, h = bh & 7;
  const int t = threadIdx.x;
  const float* const g = Gp + (long)bh * 8 * 2304;
  for (int idx = t; idx < 624; idx += 256) {
    float s = 0.f;
    if (idx < 576) {
      const int c = idx / 24, d = idx - c * 24;
      #pragma unroll
      for (int kc = 0; kc < 8; kc++) s += g[kc*2304 + c*48 + 24 + d];
      cross[idx] = s;
    } else {
      const int r = idx - 576;
      #pragma unroll
      for (int kc = 0; kc < 8; kc++) s += g[kc*2304 + r*48 + r];
      const float nv = fmaxf(sqrtf(s), 1e-12f);
      if (r < 24) qn[r] = nv; else kn[r-24] = nv;
    }
  }
  __syncthreads();
  if (t < 24) {
    const float tmp = temperature[h];
    const float qi = 1.f / qn[t];
    float vals[24];
    float m = -1e30f;
    #pragma unroll
    for (int d = 0; d < 24; d++) {
      const float v = cross[t*24 + d] * qi / kn[d] * tmp;
      vals[d] = v; m = fmaxf(m, v);
    }
    float s = 0.f;
    #pragma unroll
    for (int d = 0; d < 24; d++) { vals[d] = __expf(vals[d] - m); s += vals[d]; }
    const float inv = 1.f / s;
    #pragma unroll
    for (int d = 0; d < 24; d++) attn[(long)bh*576 + t*24 + d] = vals[d] * inv;
  }
}

// ---------------------------------------------------------------------------
// M2[b][o][g] = sum_c Wproj[o][h(g)*24+c] * attn[b][h(g)][c][d(g)]  (bf16)
// grid 1152, block 256
// ---------------------------------------------------------------------------
__global__ __launch_bounds__(256) void m2_k(
    const float* __restrict__ attn, const float* __restrict__ Wp,
    u16* __restrict__ M2)
{
  const int gid = blockIdx.x * 256 + threadIdx.x;
  const int g = gid % 192;
  const int rem = gid / 192;
  const int o = rem % 192;
  const int b = rem / 192;
  const int h = g / 24, d = g - h*24;
  const float* a = attn + ((long)(b*8 + h) * 24) * 24 + d;
  const float* w = Wp + (long)o * 192 + h * 24;
  float s = 0.f;
  #pragma unroll
  for (int c = 0; c < 24; c++) s += w[c] * a[c*24];
  M2[gid] = f2bf(s);
}

// ---------------------------------------------------------------------------
extern "C" void kernel_launch(void* const* d_in, const int* in_sizes, int n_in,
                              void* d_out, int out_size, void* d_ws, size_t ws_size,
                              hipStream_t stream) {
  const float* x    = (const float*)d_in[0];
  const float* fe   = (const float*)d_in[1];
  const float* Wqkv = (const float*)d_in[2];
  const float* Wdw  = (const float*)d_in[3];
  const float* Wpr  = (const float*)d_in[4];
  const float* temp = (const float*)d_in[5];

  char* ws = (char*)d_ws;
  u16*   xT  = (u16*)ws;                          // 50,331,648 B  [b*16384+p][192]
  u16*   vT  = xT;                                // reuse (xT dead after qkv GEMM)
  u16*   qkv = (u16*)(ws + 50331648L);            // 150,994,944 B [b][576][16384]
  float* Gp  = (float*)(ws + 201326592L);         // 4,718,592 B   [64][8][2304]
  float* attn= (float*)(ws + 206045184L);         // 147,456 B     [64][24][24]
  u16*   M2  = (u16*)(ws + 206192640L);           // 589,824 B     [b][192][192]
  u16*   Wb  = (u16*)(ws + 206782464L);           // 221,184 B     Wqkv bf16

  wcvt_k<<<54, 256, 0, stream>>>(Wqkv, Wb);
  transpose_k<true ><<<dim3(3,512,8), 256, 0, stream>>>(x, xT, 192L*16384, 0);
  gemm_dma<true, 9><<<9216, 256, 0, stream>>>(Wb, xT, qkv, 0);
  dwconv_k<<<dim3(576,8), 256, 0, stream>>>(qkv, Wdw);
  transpose_k<false><<<dim3(3,512,8), 256, 0, stream>>>(qkv, vT, 576L*16384, 384);
  gram_k<<<dim3(8,64), 256, 0, stream>>>(qkv, fe, Gp);
  attnfin_k<<<64, 256, 0, stream>>>(Gp, temp, attn);
  m2_k<<<1152, 256, 0, stream>>>(attn, Wpr, M2);
  gemm_dma<false, 3><<<3072, 256, 0, stream>>>(M2, vT, d_out, 36864L);
}